// Round 1
// baseline (267.438 us; speedup 1.0000x reference)
//
#include <hip/hip_runtime.h>

typedef __bf16 bf16;
typedef bf16 bf16x4 __attribute__((ext_vector_type(4)));
typedef bf16 bf16x8 __attribute__((ext_vector_type(8)));
typedef float f32x4 __attribute__((ext_vector_type(4)));

#define NND 98      // landmarks
#define KNB 10      // neighbors per node
#define NH 4        // heads
#define CIN 256
#define HC 64
#define XROW_B 528  // bytes per x row in LDS (264 bf16: 256 data + 8 pad -> bank spread)
#define CROW_E 140  // bf16 elems per C row in LDS (128 data + 12 pad)

// Pack W [H][2][CIN][HC] fp32 -> MFMA B-fragment order, bf16:
// Wp[hs][kt(8)][nt(4)][lane(64)][8]  with B[k = kt*32 + (lane>>4)*8 + j][n = nt*16 + (lane&15)]
__global__ __launch_bounds__(256) void prep_wp_kernel(const float* __restrict__ W,
                                                      bf16* __restrict__ Wp) {
  int t = blockIdx.x * 256 + threadIdx.x;
  if (t >= 8 * 8 * 4 * 64) return;
  int lane = t & 63;
  int nt = (t >> 6) & 3;
  int kt = (t >> 8) & 7;
  int hs = t >> 11;
  int n = nt * 16 + (lane & 15);
  int kb = kt * 32 + (lane >> 4) * 8;
  const float* src = W + (hs * CIN + kb) * HC + n;
  bf16x8 v;
#pragma unroll
  for (int j = 0; j < 8; ++j) v[j] = (bf16)src[j * HC];
  *(bf16x8*)(Wp + (long long)t * 8) = v;
}

__global__ __launch_bounds__(256, 2) void semgconv_kernel(
    const float* __restrict__ x, const float* __restrict__ e,
    const float* __restrict__ bias, const int* __restrict__ cols,
    const bf16* __restrict__ Wp, float* __restrict__ out, int B) {
  // union region: x tile (112 x 528 B bf16 row-major) then C tile (112 x 140 bf16)
  __shared__ __align__(16) unsigned char reg0[112 * XROW_B];  // 59136 B
  __shared__ float w_lds[NND * KNB];    // 3920 B
  __shared__ short cols_lds[NND * KNB]; // 1960 B
  __shared__ float diag_lds[NND];       // 392 B   -> total 65408 B

  const int tid = threadIdx.x;
  const int bid = blockIdx.x;
  const int b = bid >> 2;
  const int h = bid & 3;

  // ---- phase 0: per-row softmax over K edge logits; split out the self-edge (diag) ----
  if (tid < NND) {
    const int i = tid;
    const float* ep = e + (h * NND + i) * KNB;
    const int* cp = cols + i * KNB;
    float ev[KNB]; int cv[KNB];
    float mx = -3.0e38f;
#pragma unroll
    for (int j = 0; j < KNB; ++j) { ev[j] = ep[j]; cv[j] = cp[j]; mx = fmaxf(mx, ev[j]); }
    float s = 0.f;
#pragma unroll
    for (int j = 0; j < KNB; ++j) { ev[j] = __expf(ev[j] - mx); s += ev[j]; }
    const float inv = 1.f / s;
    float dg = 0.f;
#pragma unroll
    for (int j = 0; j < KNB; ++j) {
      float wvv = ev[j] * inv;
      if (cv[j] == i) { dg = wvv; wvv = 0.f; }  // A_off zeroes diagonal; diag scales h0
      w_lds[i * KNB + j] = wvv;
      cols_lds[i * KNB + j] = (short)cv[j];
    }
    diag_lds[i] = dg;
  }

  // ---- phase 1: stage x[b] -> LDS bf16 row-major, rows 98..111 zero-padded ----
  {
    const float* xb = x + (long long)b * NND * CIN;
#pragma unroll
    for (int it = 0; it < 28; ++it) {
      int idx = tid + it * 256;          // 112*64 float4-chunks
      int n = idx >> 6;
      int c4 = (idx & 63) << 2;
      f32x4 v = {0.f, 0.f, 0.f, 0.f};
      if (n < NND) v = *(const f32x4*)(xb + n * CIN + c4);
      bf16x4 bv;
      bv[0] = (bf16)v[0]; bv[1] = (bf16)v[1]; bv[2] = (bf16)v[2]; bv[3] = (bf16)v[3];
      *(bf16x4*)(reg0 + n * XROW_B + c4 * 2) = bv;
    }
  }
  __syncthreads();

  // ---- phase 2: MFMA GEMM  [112x256 bf16] @ [256x128 bf16] -> fp32 acc ----
  const int lane = tid & 63;
  const int wv = tid >> 6;
  const int wn = wv & 1;    // 0: s=0 (cols 0..63 = h0), 1: s=1 (cols 64..127 = h1)
  const int wm = wv >> 1;   // M-half: wm=0 -> mt 0..3, wm=1 -> mt 4..6
  const int mt0 = wm * 4;

  f32x4 acc[4][4] = {};
  const unsigned char* aptr = reg0 + (mt0 * 16 + (lane & 15)) * XROW_B + (lane >> 4) * 16;
  const bf16* wpl = Wp + ((long long)((h * 2 + wn) * 8 * 4 * 64) + lane) * 8;

#pragma unroll
  for (int kt = 0; kt < 8; ++kt) {
    bf16x8 bfr[4];
#pragma unroll
    for (int p = 0; p < 4; ++p)
      bfr[p] = *(const bf16x8*)(wpl + (kt * 4 + p) * 64 * 8);
    bf16x8 afr[4];
#pragma unroll
    for (int im = 0; im < 4; ++im)
      if (mt0 + im < 7)
        afr[im] = *(const bf16x8*)(aptr + im * (16 * XROW_B) + kt * 64);
#pragma unroll
    for (int im = 0; im < 4; ++im)
      if (mt0 + im < 7) {
#pragma unroll
        for (int p = 0; p < 4; ++p)
          acc[im][p] =
              __builtin_amdgcn_mfma_f32_16x16x32_bf16(afr[im], bfr[p], acc[im][p], 0, 0, 0);
      }
  }
  __syncthreads();  // all A-frag reads done; safe to overwrite reg0 with C

  // ---- phase 3: write C tiles (bf16) to LDS. C/D layout: col=lane&15, row=quad*4+r ----
  {
    bf16* C = (bf16*)reg0;
#pragma unroll
    for (int im = 0; im < 4; ++im)
      if (mt0 + im < 7) {
        int rowb = (mt0 + im) * 16 + (lane >> 4) * 4;
#pragma unroll
        for (int p = 0; p < 4; ++p) {
          int col = (wn * 4 + p) * 16 + (lane & 15);
#pragma unroll
          for (int r = 0; r < 4; ++r)
            C[(rowb + r) * CROW_E + col] = (bf16)acc[im][p][r];
        }
      }
  }
  __syncthreads();

  // ---- phase 4: gather-aggregate + bias, store fp32 ----
  {
    const bf16* C = (const bf16*)reg0;
    const int ig = tid >> 4;          // 16 threads per node row
    const int d4 = (tid & 15) * 4;    // 4 channels per thread
    f32x4 bs = *(const f32x4*)(bias + h * HC + d4);
    float* outp = out + (long long)b * NND * (NH * HC) + h * HC + d4;
#pragma unroll
    for (int ib = 0; ib < 7; ++ib) {
      int i = ib * 16 + ig;
      if (i < NND) {
        f32x4 av = bs;
        float dg = diag_lds[i];
        bf16x4 c0 = *(const bf16x4*)(C + i * CROW_E + d4);
        av[0] += dg * (float)c0[0];
        av[1] += dg * (float)c0[1];
        av[2] += dg * (float)c0[2];
        av[3] += dg * (float)c0[3];
#pragma unroll
        for (int j = 0; j < KNB; ++j) {
          float wj = w_lds[i * KNB + j];
          int cj = cols_lds[i * KNB + j];
          bf16x4 c1 = *(const bf16x4*)(C + cj * CROW_E + HC + d4);
          av[0] += wj * (float)c1[0];
          av[1] += wj * (float)c1[1];
          av[2] += wj * (float)c1[2];
          av[3] += wj * (float)c1[3];
        }
        *(f32x4*)(outp + (long long)i * (NH * HC)) = av;
      }
    }
  }
}

extern "C" void kernel_launch(void* const* d_in, const int* in_sizes, int n_in,
                              void* d_out, int out_size, void* d_ws, size_t ws_size,
                              hipStream_t stream) {
  const float* x    = (const float*)d_in[0];
  const float* W    = (const float*)d_in[1];
  const float* e    = (const float*)d_in[2];
  const float* bias = (const float*)d_in[3];
  // d_in[4] = rows: unused (fixed pattern: row i owns edges i*K .. i*K+K-1)
  const int* cols   = (const int*)d_in[5];
  float* out        = (float*)d_out;
  bf16* Wp          = (bf16*)d_ws;   // 131072 bf16 = 256 KiB of scratch

  int B = in_sizes[0] / (NND * CIN);  // 1024

  prep_wp_kernel<<<64, 256, 0, stream>>>(W, Wp);
  semgconv_kernel<<<B * NH, 256, 0, stream>>>(x, e, bias, cols, Wp, out, B);
}

// Round 2
// 257.833 us; speedup vs baseline: 1.0373x; 1.0373x over previous
//
#include <hip/hip_runtime.h>

typedef __bf16 bf16;
typedef bf16 bf16x4 __attribute__((ext_vector_type(4)));
typedef bf16 bf16x8 __attribute__((ext_vector_type(8)));
typedef float f32x4 __attribute__((ext_vector_type(4)));

#define NND 98      // landmarks
#define KNB 10      // neighbors per node
#define NH 4        // heads
#define CIN 256
#define HC 64
#define XROW_B 528  // bytes per x row in LDS (264 bf16: 256 data + 8 pad)
#define CROW_E 136  // bf16 elems per C row in LDS (128 data + 8 pad)

// Pack W [H][2][CIN][HC] fp32 -> MFMA B-fragment order, bf16:
// Wp[hs][kt(8)][nt(4)][lane(64)][8]  with B[k = kt*32 + (lane>>4)*8 + j][n = nt*16 + (lane&15)]
__global__ __launch_bounds__(256) void prep_wp_kernel(const float* __restrict__ W,
                                                      bf16* __restrict__ Wp) {
  int t = blockIdx.x * 256 + threadIdx.x;
  if (t >= 8 * 8 * 4 * 64) return;
  int lane = t & 63;
  int nt = (t >> 6) & 3;
  int kt = (t >> 8) & 7;
  int hs = t >> 11;
  int n = nt * 16 + (lane & 15);
  int kb = kt * 32 + (lane >> 4) * 8;
  const float* src = W + (hs * CIN + kb) * HC + n;
  bf16x8 v;
#pragma unroll
  for (int j = 0; j < 8; ++j) v[j] = (bf16)src[j * HC];
  *(bf16x8*)(Wp + (long long)t * 8) = v;
}

// One block per batch item b; all 4 heads. 1024 threads = 16 waves.
// Wave wv: wh = wv&3 (head), wm = wv>>2 (M-group of 2 tiles).
__global__ __launch_bounds__(1024, 4) void semgconv_kernel(
    const float* __restrict__ x, const float* __restrict__ e,
    const float* __restrict__ bias, const int* __restrict__ cols,
    const bf16* __restrict__ Wp, float* __restrict__ out) {
  // union region: x tile (112 x 528 B) during GEMM, then per-head C tile (112 x 136 bf16)
  __shared__ __align__(16) unsigned char reg0[112 * XROW_B];  // 59136 B
  __shared__ float w_lds[NND * KNB];    // 3920 B (one head at a time)
  __shared__ short cols_lds[NND * KNB]; // 1960 B
  __shared__ float diag_lds[NND];       // 392 B   -> total 65408 B

  const int tid = threadIdx.x;
  const int b = blockIdx.x;

  // ---- phase 0: neighbor indices -> LDS (shared by all heads) ----
  if (tid < NND) {
    const int* cp = cols + tid * KNB;
#pragma unroll
    for (int j = 0; j < KNB; ++j) cols_lds[tid * KNB + j] = (short)cp[j];
  }

  // ---- phase 1: stage x[b] -> LDS bf16 row-major, rows 98..111 zero ----
  {
    const float* xb = x + (long long)b * NND * CIN;
#pragma unroll
    for (int it = 0; it < 7; ++it) {
      int idx = tid + it * 1024;         // 112*64 float4-chunks
      int n = idx >> 6;
      int c4 = (idx & 63) << 2;
      f32x4 v = {0.f, 0.f, 0.f, 0.f};
      if (n < NND) v = *(const f32x4*)(xb + n * CIN + c4);
      bf16x4 bv;
      bv[0] = (bf16)v[0]; bv[1] = (bf16)v[1]; bv[2] = (bf16)v[2]; bv[3] = (bf16)v[3];
      *(bf16x4*)(reg0 + n * XROW_B + c4 * 2) = bv;
    }
  }
  __syncthreads();

  // ---- phase 2: MFMA GEMM [112x256 bf16] @ [256x512 bf16] -> fp32 acc ----
  const int lane = tid & 63;
  const int wv = tid >> 6;
  const int wh = wv & 3;   // head
  const int wm = wv >> 2;  // M-group: tiles {2wm, 2wm+1}, wm=3 -> tile 6 only
  const int mt0 = wm * 2;

  f32x4 acc[2][8] = {};  // [im][q], q = s*4+nt -> cols q*16 .. q*16+15 of head wh
  const unsigned char* aptr = reg0 + (mt0 * 16 + (lane & 15)) * XROW_B + (lane >> 4) * 16;
  const bf16* wpl = Wp + ((long long)(wh * 2) * (8 * 4 * 64) + lane) * 8;  // hs = wh*2

#pragma unroll
  for (int kt = 0; kt < 8; ++kt) {
    bf16x8 afr[2];
#pragma unroll
    for (int im = 0; im < 2; ++im)
      if (mt0 + im < 7)
        afr[im] = *(const bf16x8*)(aptr + im * (16 * XROW_B) + kt * 64);
    // first head-half (s=0): q = 0..3
    {
      bf16x8 bfr[4];
#pragma unroll
      for (int nt = 0; nt < 4; ++nt)
        bfr[nt] = *(const bf16x8*)(wpl + ((kt * 4 + nt) * 64) * 8);
#pragma unroll
      for (int im = 0; im < 2; ++im)
        if (mt0 + im < 7)
#pragma unroll
          for (int nt = 0; nt < 4; ++nt)
            acc[im][nt] = __builtin_amdgcn_mfma_f32_16x16x32_bf16(afr[im], bfr[nt],
                                                                  acc[im][nt], 0, 0, 0);
    }
    // second head-half (s=1): q = 4..7
    {
      bf16x8 bfr[4];
#pragma unroll
      for (int nt = 0; nt < 4; ++nt)
        bfr[nt] = *(const bf16x8*)(wpl + ((8 * 4 + kt * 4 + nt) * 64) * 8);
#pragma unroll
      for (int im = 0; im < 2; ++im)
        if (mt0 + im < 7)
#pragma unroll
          for (int nt = 0; nt < 4; ++nt)
            acc[im][4 + nt] = __builtin_amdgcn_mfma_f32_16x16x32_bf16(afr[im], bfr[nt],
                                                                      acc[im][4 + nt], 0, 0, 0);
    }
  }
  __syncthreads();  // all A-frag reads done; reg0 reusable as C

  // ---- epilogue: 4 per-head rounds ----
  bf16* C = (bf16*)reg0;
  const int ig = tid >> 4;         // 0..63: node-row slot
  const int d4 = (tid & 15) * 4;   // 4 channels per thread

  for (int h = 0; h < NH; ++h) {
    // per-head softmax (threads 0..97)
    if (tid < NND) {
      const int i = tid;
      const float* ep = e + (h * NND + i) * KNB;
      float ev[KNB];
      float mx = -3.0e38f;
#pragma unroll
      for (int j = 0; j < KNB; ++j) { ev[j] = ep[j]; mx = fmaxf(mx, ev[j]); }
      float s = 0.f;
#pragma unroll
      for (int j = 0; j < KNB; ++j) { ev[j] = __expf(ev[j] - mx); s += ev[j]; }
      const float inv = 1.f / s;
      float dg = 0.f;
#pragma unroll
      for (int j = 0; j < KNB; ++j) {
        float wvv = ev[j] * inv;
        if ((int)cols_lds[i * KNB + j] == i) { dg = wvv; wvv = 0.f; }
        w_lds[i * KNB + j] = wvv;
      }
      diag_lds[i] = dg;
    }
    // C-write: waves of head h dump their acc (bf16) into LDS
    if (wh == h) {
#pragma unroll
      for (int im = 0; im < 2; ++im) {
        int mt = mt0 + im;
        if (mt < 7) {
          int rowb = mt * 16 + (lane >> 4) * 4;
#pragma unroll
          for (int q = 0; q < 8; ++q) {
            int col = q * 16 + (lane & 15);
#pragma unroll
            for (int r = 0; r < 4; ++r)
              C[(rowb + r) * CROW_E + col] = (bf16)acc[im][q][r];
          }
        }
      }
    }
    __syncthreads();

    // gather-aggregate + bias, store fp32
    {
      f32x4 bs = *(const f32x4*)(bias + h * HC + d4);
      float* outp = out + (long long)b * NND * (NH * HC) + h * HC + d4;
#pragma unroll
      for (int ib = 0; ib < 2; ++ib) {
        int i = ib * 64 + ig;
        if (i < NND) {
          f32x4 av = bs;
          float dg = diag_lds[i];
          bf16x4 c0 = *(const bf16x4*)(C + i * CROW_E + d4);
          av[0] += dg * (float)c0[0];
          av[1] += dg * (float)c0[1];
          av[2] += dg * (float)c0[2];
          av[3] += dg * (float)c0[3];
#pragma unroll
          for (int j = 0; j < KNB; ++j) {
            float wj = w_lds[i * KNB + j];
            int cj = (int)cols_lds[i * KNB + j];
            bf16x4 c1 = *(const bf16x4*)(C + cj * CROW_E + HC + d4);
            av[0] += wj * (float)c1[0];
            av[1] += wj * (float)c1[1];
            av[2] += wj * (float)c1[2];
            av[3] += wj * (float)c1[3];
          }
          *(f32x4*)(outp + (long long)i * (NH * HC)) = av;
        }
      }
    }
    __syncthreads();  // protect C/w_lds before next round overwrites
  }
}

extern "C" void kernel_launch(void* const* d_in, const int* in_sizes, int n_in,
                              void* d_out, int out_size, void* d_ws, size_t ws_size,
                              hipStream_t stream) {
  const float* x    = (const float*)d_in[0];
  const float* W    = (const float*)d_in[1];
  const float* e    = (const float*)d_in[2];
  const float* bias = (const float*)d_in[3];
  // d_in[4] = rows: unused (fixed pattern: row i owns edges i*K .. i*K+K-1)
  const int* cols   = (const int*)d_in[5];
  float* out        = (float*)d_out;
  bf16* Wp          = (bf16*)d_ws;   // 131072 bf16 = 256 KiB of scratch

  int B = in_sizes[0] / (NND * CIN);  // 1024

  prep_wp_kernel<<<64, 256, 0, stream>>>(W, Wp);
  semgconv_kernel<<<B, 1024, 0, stream>>>(x, e, bias, cols, Wp, out);
}